// Round 1
// baseline (304.611 us; speedup 1.0000x reference)
//
#include <hip/hip_runtime.h>

// Problem: TextualKnowledgeInjector  B=64 T=256 F=40 D=768 H=256
// out[b,t,h] = (sum_{i<j, avail, m_i&m_j} dot(E[i,j,:], W[h,:])) / max(cnt,1) + bias[h]
// Key identity: (ctx_sum/cnt)@W^T == (ctx_sum@W^T)/cnt  (cnt is per-row scalar)
// => precompute EW[p][h] = dot(E[i_p,j_p,:], W[h,:]) for the 780 i<j pairs once,
//    then each row is a ~97-pair gather-sum over 256-wide EW rows.

#define FF 40
#define DD 768
#define HH 256
#define NPAIR 780  // 40*39/2
#define NROW 16384 // B*T

// ---------------- kernel 0: avail bitmasks (j>i only) ----------------
__global__ void k_avail(const int* __restrict__ pa, unsigned long long* __restrict__ availw) {
    int i = threadIdx.x;
    if (i < FF) {
        unsigned long long bits = 0ull;
        for (int j = i + 1; j < FF; ++j)
            if (pa[i * FF + j] != 0) bits |= (1ull << j);
        availw[i] = bits;
    }
}

// ---------------- kernel 1: EW[p][h] = dot(E[i,j,:], W[h,:]) ----------------
__global__ __launch_bounds__(256) void k_ew(const float* __restrict__ E,
                                            const int* __restrict__ pa,
                                            const float* __restrict__ W,
                                            float* __restrict__ EW) {
    int p = blockIdx.x;
    // decode triangular index p -> (i, j), i<j
    int i = 0;
    while (i + 1 < FF && ((i + 1) * (FF - 1) - (i + 1) * i / 2) <= p) ++i;
    int base = i * (FF - 1) - i * (i - 1) / 2;
    int j = p - base + i + 1;
    if (pa[i * FF + j] == 0) return;  // this EW row is never read (avail bit masks it)

    __shared__ float4 e4[DD / 4];  // 192 float4 = 3 KB
    int tid = threadIdx.x;
    const float4* esrc = (const float4*)(E + (size_t)(i * FF + j) * DD);
    if (tid < DD / 4) e4[tid] = esrc[tid];
    __syncthreads();

    const float4* w4 = (const float4*)(W + (size_t)tid * DD);
    float acc = 0.f;
#pragma unroll 4
    for (int d = 0; d < DD / 4; ++d) {
        float4 a = e4[d];
        float4 b = w4[d];
        acc += a.x * b.x + a.y * b.y + a.z * b.z + a.w * b.w;
    }
    EW[(size_t)p * HH + tid] = acc;
}

// ---------------- kernel 2: per-row gather + scale + bias ----------------
__global__ __launch_bounds__(256) void k_main(const int* __restrict__ sm,
                                              const unsigned long long* __restrict__ availw,
                                              const float* __restrict__ EW,
                                              const float* __restrict__ bias,
                                              float* __restrict__ out) {
    int row = blockIdx.x;
    int tid = threadIdx.x;
    __shared__ unsigned long long smask;
    __shared__ unsigned long long aw[FF];

    if (tid < 64) {  // wave 0 builds the 40-bit row mask
        int v = (tid < FF) ? sm[(size_t)row * FF + tid] : 0;
        unsigned long long b = __ballot(v != 0);
        if (tid == 0) smask = b;
    }
    if (tid < FF) aw[tid] = availw[tid];
    __syncthreads();

    unsigned long long m = smask;
    float acc = 0.f;
    int cnt = 0;
    for (int i = 0; i < FF; ++i) {
        if ((m >> i) & 1ull) {
            unsigned long long bits = m & aw[i];  // present j>i with avail
            cnt += __popcll(bits);
            int base = i * (FF - 1) - i * (i - 1) / 2 - i - 1;
            while (bits) {
                int j = __builtin_ctzll(bits);
                bits &= bits - 1;
                acc += EW[(size_t)(base + j) * HH + tid];
            }
        }
    }
    float denom = (cnt > 0) ? (float)cnt : 1.0f;
    out[(size_t)row * HH + tid] = acc / denom + bias[tid];
}

extern "C" void kernel_launch(void* const* d_in, const int* in_sizes, int n_in,
                              void* d_out, int out_size, void* d_ws, size_t ws_size,
                              hipStream_t stream) {
    const int*   sm   = (const int*)d_in[0];    // surviving_mask [B,T,F] bool->int
    const float* E    = (const float*)d_in[1];  // pair_emb [F,F,D] f32
    const int*   pa   = (const int*)d_in[2];    // pair_avail [F,F] bool->int
    const float* W    = (const float*)d_in[3];  // adapter_w [H,D] f32
    const float* bias = (const float*)d_in[4];  // adapter_b [H] f32
    float* out = (float*)d_out;

    // ws layout: [0,320) availw u64[40]; [1024, 1024+780*256*4) EW  (~800 KB total)
    unsigned long long* availw = (unsigned long long*)d_ws;
    float* EW = (float*)((char*)d_ws + 1024);

    hipLaunchKernelGGL(k_avail, dim3(1), dim3(64), 0, stream, pa, availw);
    hipLaunchKernelGGL(k_ew, dim3(NPAIR), dim3(256), 0, stream, E, pa, W, EW);
    hipLaunchKernelGGL(k_main, dim3(NROW), dim3(256), 0, stream, sm, availw, EW, bias, out);
}

// Round 2
// 123.177 us; speedup vs baseline: 2.4730x; 2.4730x over previous
//
#include <hip/hip_runtime.h>
#include <hip/hip_bf16.h>

// TextualKnowledgeInjector  B=64 T=256 F=40 D=768 H=256
// out[r,h] = (sum_{p in avail pairs, both present} EW[p,h]) / max(cnt_r,1) + bias[h]
// Reformulated as two MFMA GEMMs:
//   GEMM1: EWt[h][p] = sum_d Wbf[h][d] * Ebf[p][d]      (M=256,N=896,K=768)
//   GEMM2: out[r][h] = (sum_p S[r][p] * EWt[h][p]) * rcp(cnt_r) + bias[h]
//          (M=16384,N=256,K=896), S built on the fly from per-row bit-bytes.

#define FF 40
#define DD 768
#define HH 256
#define NPADJ 896      // padded pair count (multiple of 128)
#define NPREAL 780
#define NROWS 16384
#define SBS 112        // S-bit bytes per row = NPADJ/8

typedef short s8v __attribute__((ext_vector_type(8)));
typedef float f4v __attribute__((ext_vector_type(4)));
typedef unsigned short ushort_t;

__device__ __forceinline__ void gload16(const void* g, void* l) {
    __builtin_amdgcn_global_load_lds(
        (const __attribute__((address_space(1))) unsigned int*)g,
        (__attribute__((address_space(3))) unsigned int*)l, 16, 0, 0);
}

__device__ __forceinline__ ushort_t f2b(float f) {
    __hip_bfloat16 h = __float2bfloat16(f);
    return *(ushort_t*)&h;
}

// ---------------- setup: pair masks + pair->E row (1 block) ----------------
__global__ void k_setup(const int* __restrict__ pa,
                        unsigned long long* __restrict__ pm,
                        int* __restrict__ pairRow) {
    for (int p = threadIdx.x; p < NPADJ; p += 256) {
        unsigned long long v = ~0ull;  // never satisfied by a 40-bit mask -> S=0
        int row = 0;
        if (p < NPREAL) {
            int i = 0, base = 0;
            while (base + (FF - 1 - i) <= p) { base += FF - 1 - i; ++i; }
            int j = i + 1 + (p - base);
            row = i * FF + j;
            if (pa[row] != 0) v = (1ull << i) | (1ull << j);
        }
        pm[p] = v;
        pairRow[p] = row;
    }
}

// ---------------- gather+cast E pairs and W to bf16 ----------------
// grid: (896+256)*96/256 = 432 blocks; each thread converts 8 elems
__global__ __launch_bounds__(256) void k_cast(const float* __restrict__ E,
                                              const float* __restrict__ W,
                                              const int* __restrict__ pairRow,
                                              ushort_t* __restrict__ Ebf,
                                              ushort_t* __restrict__ Wbf) {
    int t = blockIdx.x * 256 + threadIdx.x;
    int r = t / 96, c8 = (t % 96) * 8;
    const float* src;
    ushort_t* dst;
    if (r < NPADJ) {
        src = E + (size_t)pairRow[r] * DD + c8;
        dst = Ebf + (size_t)r * DD + c8;
    } else {
        int rw = r - NPADJ;
        src = W + (size_t)rw * DD + c8;
        dst = Wbf + (size_t)rw * DD + c8;
    }
    float4 f0 = ((const float4*)src)[0];
    float4 f1 = ((const float4*)src)[1];
    unsigned w0 = (unsigned)f2b(f0.x) | ((unsigned)f2b(f0.y) << 16);
    unsigned w1 = (unsigned)f2b(f0.z) | ((unsigned)f2b(f0.w) << 16);
    unsigned w2 = (unsigned)f2b(f1.x) | ((unsigned)f2b(f1.y) << 16);
    unsigned w3 = (unsigned)f2b(f1.z) | ((unsigned)f2b(f1.w) << 16);
    uint4 q; q.x = w0; q.y = w1; q.z = w2; q.w = w3;
    *(uint4*)dst = q;
}

// ---------------- per-row S bytes + 1/cnt (1 wave per row) ----------------
__global__ __launch_bounds__(256) void k_mask(const int* __restrict__ sm,
                                              const unsigned long long* __restrict__ pm,
                                              unsigned char* __restrict__ sbytes,
                                              float* __restrict__ cntrcp) {
    int wid = threadIdx.x >> 6, lane = threadIdx.x & 63;
    int row = blockIdx.x * 4 + wid;
    int v = (lane < FF) ? sm[(size_t)row * FF + lane] : 0;
    unsigned long long mask = __ballot(v != 0);
    int c = 0;
#pragma unroll
    for (int rep = 0; rep < 2; ++rep) {
        int b = lane + rep * 64;
        if (b < SBS) {
            int p0 = b * 8;
            unsigned bits = 0;
#pragma unroll
            for (int e = 0; e < 8; ++e) {
                unsigned long long q = pm[p0 + e];
                bits |= ((mask & q) == q) ? (1u << e) : 0u;
            }
            sbytes[(size_t)row * SBS + b] = (unsigned char)bits;
            c += __popc(bits);
        }
    }
#pragma unroll
    for (int o = 32; o > 0; o >>= 1) c += __shfl_xor(c, o, 64);
    if (lane == 0) cntrcp[row] = 1.0f / (float)(c > 0 ? c : 1);
}

// ---------------- GEMM1: EWt = Wbf (256xK) x Ebf^T (Kx896), K=768 ----------------
__global__ __launch_bounds__(256) void k_gemm1(const ushort_t* __restrict__ Wbf,
                                               const ushort_t* __restrict__ Ebf,
                                               ushort_t* __restrict__ EWt) {
    __shared__ char As[2][8192];
    __shared__ char Bs[2][8192];
    int tid = threadIdx.x, lane = tid & 63, wid = tid >> 6;
    int r0 = blockIdx.x * 128;  // h tile
    int c0 = blockIdx.y * 128;  // p tile
    int wr = wid >> 1, wc = wid & 1;

    f4v acc[4][4];
#pragma unroll
    for (int m = 0; m < 4; ++m)
#pragma unroll
        for (int n = 0; n < 4; ++n) acc[m][n] = (f4v)0.0f;

    auto stage = [&](int bi, int kb) {
#pragma unroll
        for (int rep = 0; rep < 2; ++rep) {
            int X = (rep * 256 + tid) * 16;
            int L = X ^ (((X >> 6) & 3) << 4);   // inverse slot swizzle
            int rrow = L >> 6, koffB = L & 63;
            gload16((const char*)Wbf + (((size_t)(r0 + rrow)) * DD + kb) * 2 + koffB,
                    As[bi] + X);
            gload16((const char*)Ebf + (((size_t)(c0 + rrow)) * DD + kb) * 2 + koffB,
                    Bs[bi] + X);
        }
    };

    stage(0, 0);
    __syncthreads();
    const int NT = DD / 32;  // 24
    for (int t = 0; t < NT; ++t) {
        int cur = t & 1;
        if (t + 1 < NT) stage(cur ^ 1, (t + 1) * 32);
        s8v a[4], b[4];
        int kg = (lane >> 4) * 16;
#pragma unroll
        for (int m = 0; m < 4; ++m) {
            int row = wr * 64 + m * 16 + (lane & 15);
            a[m] = *(const s8v*)(As[cur] + ((row * 64 + kg) ^ ((row & 3) << 4)));
        }
#pragma unroll
        for (int n = 0; n < 4; ++n) {
            int row = wc * 64 + n * 16 + (lane & 15);
            b[n] = *(const s8v*)(Bs[cur] + ((row * 64 + kg) ^ ((row & 3) << 4)));
        }
#pragma unroll
        for (int m = 0; m < 4; ++m)
#pragma unroll
            for (int n = 0; n < 4; ++n)
                acc[m][n] = __builtin_amdgcn_mfma_f32_16x16x32_bf16(a[m], b[n], acc[m][n], 0, 0, 0);
        __syncthreads();
    }
#pragma unroll
    for (int m = 0; m < 4; ++m)
#pragma unroll
        for (int n = 0; n < 4; ++n) {
            int colp = c0 + wc * 64 + n * 16 + (lane & 15);
#pragma unroll
            for (int r = 0; r < 4; ++r) {
                int rowh = r0 + wr * 64 + m * 16 + (lane >> 4) * 4 + r;
                EWt[(size_t)rowh * NPADJ + colp] = f2b(acc[m][n][r]);
            }
        }
}

// ---------------- GEMM2: out = S (16384xK) x EWt^T (Kx256), K=896 ----------------
__global__ __launch_bounds__(256) void k_gemm2(const unsigned char* __restrict__ sbytes,
                                               const ushort_t* __restrict__ EWt,
                                               const float* __restrict__ cntrcp,
                                               const float* __restrict__ bias,
                                               float* __restrict__ out) {
    __shared__ char Sb[14336];    // 128 rows x 112 S-bit bytes
    __shared__ char LUT[4096];    // byte -> 8 bf16 {0,1}
    __shared__ char Bs[2][8192];
    int tid = threadIdx.x, lane = tid & 63, wid = tid >> 6;
    int r0 = blockIdx.x * 128;  // row tile
    int c0 = blockIdx.y * 128;  // h tile
    int wr = wid >> 1, wc = wid & 1;

    {   // build LUT: entry e, elem i = bit i of e as bf16
        unsigned e = tid;
        uint4 q;
        q.x = ((e & 1) ? 0x3F80u : 0u) | ((e & 2) ? 0x3F800000u : 0u);
        q.y = ((e & 4) ? 0x3F80u : 0u) | ((e & 8) ? 0x3F800000u : 0u);
        q.z = ((e & 16) ? 0x3F80u : 0u) | ((e & 32) ? 0x3F800000u : 0u);
        q.w = ((e & 64) ? 0x3F80u : 0u) | ((e & 128) ? 0x3F800000u : 0u);
        *(uint4*)(LUT + e * 16) = q;
    }
    // stage this block's 128x112 S-byte panel (contiguous in global)
    for (int rep = 0; rep < 4; ++rep) {
        int cch = rep * 256 + tid;
        if (cch < 896) gload16(sbytes + (size_t)r0 * SBS + (size_t)cch * 16, Sb + cch * 16);
    }

    auto stageB = [&](int bi, int kb) {
#pragma unroll
        for (int rep = 0; rep < 2; ++rep) {
            int X = (rep * 256 + tid) * 16;
            int L = X ^ (((X >> 6) & 3) << 4);
            int nrow = L >> 6, koffB = L & 63;
            gload16((const char*)EWt + (((size_t)(c0 + nrow)) * NPADJ + kb) * 2 + koffB,
                    Bs[bi] + X);
        }
    };
    stageB(0, 0);

    f4v acc[4][4];
#pragma unroll
    for (int m = 0; m < 4; ++m)
#pragma unroll
        for (int n = 0; n < 4; ++n) acc[m][n] = (f4v)0.0f;

    __syncthreads();
    const int NT = NPADJ / 32;  // 28
    for (int t = 0; t < NT; ++t) {
        int cur = t & 1;
        if (t + 1 < NT) stageB(cur ^ 1, (t + 1) * 32);
        s8v a[4], b[4];
        int kgrp = lane >> 4;
#pragma unroll
        for (int m = 0; m < 4; ++m) {
            int row = wr * 64 + m * 16 + (lane & 15);
            unsigned by = *(const unsigned char*)(Sb + row * SBS + t * 4 + kgrp);
            a[m] = *(const s8v*)(LUT + by * 16);
        }
#pragma unroll
        for (int n = 0; n < 4; ++n) {
            int row = wc * 64 + n * 16 + (lane & 15);
            b[n] = *(const s8v*)(Bs[cur] + ((row * 64 + kgrp * 16) ^ ((row & 3) << 4)));
        }
#pragma unroll
        for (int m = 0; m < 4; ++m)
#pragma unroll
            for (int n = 0; n < 4; ++n)
                acc[m][n] = __builtin_amdgcn_mfma_f32_16x16x32_bf16(a[m], b[n], acc[m][n], 0, 0, 0);
        __syncthreads();
    }
    // epilogue: scale by 1/cnt, add bias
#pragma unroll
    for (int m = 0; m < 4; ++m) {
        int rbase = r0 + wr * 64 + m * 16 + (lane >> 4) * 4;
        float rc[4];
#pragma unroll
        for (int r = 0; r < 4; ++r) rc[r] = cntrcp[rbase + r];
#pragma unroll
        for (int n = 0; n < 4; ++n) {
            int col = c0 + wc * 64 + n * 16 + (lane & 15);
            float bv = bias[col];
#pragma unroll
            for (int r = 0; r < 4; ++r)
                out[(size_t)(rbase + r) * HH + col] = acc[m][n][r] * rc[r] + bv;
        }
    }
}

extern "C" void kernel_launch(void* const* d_in, const int* in_sizes, int n_in,
                              void* d_out, int out_size, void* d_ws, size_t ws_size,
                              hipStream_t stream) {
    const int*   sm   = (const int*)d_in[0];    // surviving_mask [B,T,F]
    const float* E    = (const float*)d_in[1];  // pair_emb [F,F,D]
    const int*   pa   = (const int*)d_in[2];    // pair_avail [F,F]
    const float* W    = (const float*)d_in[3];  // adapter_w [H,D]
    const float* bias = (const float*)d_in[4];  // adapter_b [H]
    float* out = (float*)d_out;

    // workspace layout (bytes)
    char* ws = (char*)d_ws;
    unsigned long long* pm      = (unsigned long long*)(ws + 0);        // 7168
    int*                pairRow = (int*)(ws + 7168);                    // 3584
    float*              cntrcp  = (float*)(ws + 10752);                 // 65536
    ushort_t*           Ebf     = (ushort_t*)(ws + 76288);              // 1376256
    ushort_t*           Wbf     = (ushort_t*)(ws + 1452544);            // 393216
    ushort_t*           EWt     = (ushort_t*)(ws + 1845760);            // 458752
    unsigned char*      sbytes  = (unsigned char*)(ws + 2304512);       // 1835008 -> 4.14 MB

    hipLaunchKernelGGL(k_setup, dim3(1), dim3(256), 0, stream, pa, pm, pairRow);
    hipLaunchKernelGGL(k_cast, dim3(432), dim3(256), 0, stream, E, W, pairRow, Ebf, Wbf);
    hipLaunchKernelGGL(k_mask, dim3(NROWS / 4), dim3(256), 0, stream, sm, pm, sbytes, cntrcp);
    hipLaunchKernelGGL(k_gemm1, dim3(2, 7), dim3(256), 0, stream, Wbf, Ebf, EWt);
    hipLaunchKernelGGL(k_gemm2, dim3(128, 2), dim3(256), 0, stream, sbytes, EWt, cntrcp, bias, out);
}

// Round 4
// 98.608 us; speedup vs baseline: 3.0891x; 1.2492x over previous
//
#include <hip/hip_runtime.h>
#include <hip/hip_bf16.h>

// TextualKnowledgeInjector  B=64 T=256 F=40 D=768 H=256
// out[r,h] = (sum_{p avail, both present} dot(E[i_p,j_p,:],W[h,:])) / max(cnt_r,1) + bias[h]
// Two fused launches:
//  k_front: blocks 0..55  : GEMM1  EWt[h][p] = W x E_pairs^T (256x896, K=768),
//                           fp32 inputs reg-staged + converted to bf16 inline.
//           blocks 56..311: per-row S-bit bytes + 1/cnt (pair masks built in LDS).
//  k_gemm2: out = S(16384xK) x EWt^T(Kx256), K=896, S from bytes via LDS LUT.

#define FF 40
#define DD 768
#define HH 256
#define NPADJ 896
#define NPREAL 780
#define NROWS 16384
#define SBS 112        // NPADJ/8 bytes per row
#define G1B 56         // 4 h-tiles x 14 p-tiles

typedef short s8v __attribute__((ext_vector_type(8)));
typedef float f4v __attribute__((ext_vector_type(4)));
typedef unsigned short u16;

__device__ __forceinline__ void gload16(const void* g, void* l) {
    __builtin_amdgcn_global_load_lds(
        (const __attribute__((address_space(1))) unsigned int*)g,
        (__attribute__((address_space(3))) unsigned int*)l, 16, 0, 0);
}
__device__ __forceinline__ u16 f2b(float f) {
    __hip_bfloat16 h = __float2bfloat16(f);
    return *(u16*)&h;
}
__device__ __forceinline__ unsigned pk2(float x, float y) {
    return (unsigned)f2b(x) | ((unsigned)f2b(y) << 16);
}
__device__ __forceinline__ int pair_erow(int p) {  // triangular p -> E row i*FF+j
    if (p >= NPREAL) return 0;                     // pad rows: finite garbage, S=0 masks
    int i = 0, base = 0;
    while (base + (FF - 1 - i) <= p) { base += FF - 1 - i; ++i; }
    int j = i + 1 + (p - base);
    return i * FF + j;
}

// ================= kernel 1: gemm1 + mask =================
__global__ __launch_bounds__(256) void k_front(const int* __restrict__ sm,
                                               const float* __restrict__ E,
                                               const int* __restrict__ pa,
                                               const float* __restrict__ W,
                                               u16* __restrict__ EWt,
                                               unsigned char* __restrict__ sbytes,
                                               float* __restrict__ cntrcp) {
    __shared__ __align__(16) char As[2][8192];
    __shared__ __align__(16) char Bs[2][8192];
    __shared__ unsigned long long pmT[8][SBS];
    int tid = threadIdx.x;

    if (blockIdx.x < G1B) {
        // ---- GEMM1: 64x64 tile over (h, p), K=768, BK=64 ----
        int bx = blockIdx.x / 14, by = blockIdx.x % 14;
        int r0 = bx * 64, c0 = by * 64;
        int lane = tid & 63, wid = tid >> 6;
        int wr = wid >> 1, wc = wid & 1;

        // staging slots: 4 reps; slot = tid + 256*rep; row = slot>>4, kq = slot&15 (4 f32)
        int sOff[4];
        const float* aSrc[4];
        const float* bSrc[4];
#pragma unroll
        for (int r = 0; r < 4; ++r) {
            int slot = tid + 256 * r;
            int row = slot >> 4, kq = slot & 15;
            sOff[r] = (row * 128 + kq * 8) ^ ((row & 7) << 4);
            aSrc[r] = W + (size_t)(r0 + row) * DD + kq * 4;
            bSrc[r] = E + (size_t)pair_erow(c0 + row) * DD + kq * 4;
        }
        f4v acc[2][2];
#pragma unroll
        for (int m = 0; m < 2; ++m)
#pragma unroll
            for (int n = 0; n < 2; ++n) acc[m][n] = (f4v)0.0f;

        float4 ra[4], rb[4];
#pragma unroll
        for (int r = 0; r < 4; ++r) { ra[r] = *(const float4*)aSrc[r]; rb[r] = *(const float4*)bSrc[r]; }
#pragma unroll
        for (int r = 0; r < 4; ++r) {
            *(uint2*)(As[0] + sOff[r]) = make_uint2(pk2(ra[r].x, ra[r].y), pk2(ra[r].z, ra[r].w));
            *(uint2*)(Bs[0] + sOff[r]) = make_uint2(pk2(rb[r].x, rb[r].y), pk2(rb[r].z, rb[r].w));
        }
        __syncthreads();

        const int NT = DD / 64;  // 12
        for (int t = 0; t < NT; ++t) {
            int cur = t & 1;
            if (t + 1 < NT) {
                int kb = (t + 1) * 64;
#pragma unroll
                for (int r = 0; r < 4; ++r) {
                    ra[r] = *(const float4*)(aSrc[r] + kb);
                    rb[r] = *(const float4*)(bSrc[r] + kb);
                }
            }
            int kg16 = (lane >> 4) * 16;
#pragma unroll
            for (int ks = 0; ks < 2; ++ks) {
                s8v a[2], b[2];
#pragma unroll
                for (int m = 0; m < 2; ++m) {
                    int row = wr * 32 + m * 16 + (lane & 15);
                    a[m] = *(const s8v*)(As[cur] + ((row * 128 + ks * 64 + kg16) ^ ((row & 7) << 4)));
                }
#pragma unroll
                for (int n = 0; n < 2; ++n) {
                    int row = wc * 32 + n * 16 + (lane & 15);
                    b[n] = *(const s8v*)(Bs[cur] + ((row * 128 + ks * 64 + kg16) ^ ((row & 7) << 4)));
                }
#pragma unroll
                for (int m = 0; m < 2; ++m)
#pragma unroll
                    for (int n = 0; n < 2; ++n)
                        acc[m][n] = __builtin_amdgcn_mfma_f32_16x16x32_bf16(a[m], b[n], acc[m][n], 0, 0, 0);
            }
            if (t + 1 < NT) {
                int nb = cur ^ 1;
#pragma unroll
                for (int r = 0; r < 4; ++r) {
                    *(uint2*)(As[nb] + sOff[r]) = make_uint2(pk2(ra[r].x, ra[r].y), pk2(ra[r].z, ra[r].w));
                    *(uint2*)(Bs[nb] + sOff[r]) = make_uint2(pk2(rb[r].x, rb[r].y), pk2(rb[r].z, rb[r].w));
                }
            }
            __syncthreads();
        }
#pragma unroll
        for (int m = 0; m < 2; ++m)
#pragma unroll
            for (int n = 0; n < 2; ++n) {
                int colp = c0 + wc * 32 + n * 16 + (lane & 15);
#pragma unroll
                for (int r = 0; r < 4; ++r) {
                    int rowh = r0 + wr * 32 + m * 16 + (lane >> 4) * 4 + r;
                    EWt[(size_t)rowh * NPADJ + colp] = f2b(acc[m][n][r]);
                }
            }
    } else {
        // ---- mask: 64 rows per block ----
        int mb = blockIdx.x - G1B;
        int r0 = mb * 64;
#pragma unroll
        for (int rep = 0; rep < 4; ++rep) {
            int p = rep * 256 + tid;
            if (p < NPADJ) {
                unsigned long long q = ~0ull;  // never satisfied by 40-bit mask
                if (p < NPREAL) {
                    int i = 0, base = 0;
                    while (base + (FF - 1 - i) <= p) { base += FF - 1 - i; ++i; }
                    int j = i + 1 + (p - base);
                    if (pa[i * FF + j] != 0) q = (1ull << i) | (1ull << j);
                }
                pmT[p & 7][p >> 3] = q;  // transposed: lanes read consecutive b -> 2-way (free)
            }
        }
        __syncthreads();
        int lane = tid & 63, wid = tid >> 6;
        int v = (lane < FF) ? sm[(size_t)(r0 + wid * 16) * FF + lane] : 0;
        for (int rr = 0; rr < 16; ++rr) {
            int row = r0 + wid * 16 + rr;
            int vnext = (rr + 1 < 16 && lane < FF) ? sm[(size_t)(row + 1) * FF + lane] : 0;
            unsigned long long mask = __ballot(v != 0);
            int c = 0;
#pragma unroll
            for (int rep = 0; rep < 2; ++rep) {
                int b = lane + rep * 64;
                if (b < SBS) {
                    unsigned bits = 0;
#pragma unroll
                    for (int e = 0; e < 8; ++e) {
                        unsigned long long q = pmT[e][b];
                        bits |= ((mask & q) == q) ? (1u << e) : 0u;
                    }
                    sbytes[(size_t)row * SBS + b] = (unsigned char)bits;
                    c += __popc(bits);
                }
            }
#pragma unroll
            for (int o = 32; o; o >>= 1) c += __shfl_xor(c, o, 64);
            if (lane == 0) cntrcp[row] = 1.0f / (float)(c > 0 ? c : 1);
            v = vnext;
        }
    }
}

// ================= kernel 2: out = S x EWt^T =================
__global__ __launch_bounds__(256) void k_gemm2(const unsigned char* __restrict__ sbytes,
                                               const u16* __restrict__ EWt,
                                               const float* __restrict__ cntrcp,
                                               const float* __restrict__ bias,
                                               float* __restrict__ out) {
    __shared__ __align__(16) char Sb[7168];       // 64 rows x 112 bytes
    __shared__ __align__(16) char LUT[4096];      // byte -> 8 bf16 {0,1}
    __shared__ __align__(16) char Bsm[2][16384];  // 128 h-rows x 128 B (BK=64)
    int tid = threadIdx.x, lane = tid & 63, wid = tid >> 6;
    int r0 = blockIdx.x * 64, c0 = blockIdx.y * 128;
    int wc = wid;  // each wave: 64 rows x 32 cols

    {   // LUT: entry e, elem i = bit i of e as bf16 1.0/0.0
        unsigned e = tid;
        uint4 q;
        q.x = ((e & 1) ? 0x3F80u : 0u) | ((e & 2) ? 0x3F800000u : 0u);
        q.y = ((e & 4) ? 0x3F80u : 0u) | ((e & 8) ? 0x3F800000u : 0u);
        q.z = ((e & 16) ? 0x3F80u : 0u) | ((e & 32) ? 0x3F800000u : 0u);
        q.w = ((e & 64) ? 0x3F80u : 0u) | ((e & 128) ? 0x3F800000u : 0u);
        *(uint4*)(LUT + e * 16) = q;
    }
    {   // stage Sb: 448 16B chunks (contiguous)
        gload16(sbytes + (size_t)r0 * SBS + (size_t)tid * 16, Sb + tid * 16);
        int cch = 256 + tid;
        if (cch < 448) gload16(sbytes + (size_t)r0 * SBS + (size_t)cch * 16, Sb + cch * 16);
    }
    auto stageB = [&](int bi, int kb) {
#pragma unroll
        for (int rep = 0; rep < 4; ++rep) {
            int X = (rep * 256 + tid) * 16;
            int L = X ^ (((X >> 7) & 7) << 4);  // involutive: bits4-6 <- row bits (>=7)
            int row = L >> 7, koff = L & 127;
            gload16((const char*)EWt + ((size_t)(c0 + row) * NPADJ + kb) * 2 + koff, Bsm[bi] + X);
        }
    };
    stageB(0, 0);

    f4v acc[4][2];
#pragma unroll
    for (int m = 0; m < 4; ++m)
#pragma unroll
        for (int n = 0; n < 2; ++n) acc[m][n] = (f4v)0.0f;
    __syncthreads();

    const int NT = NPADJ / 64;  // 14
    for (int t = 0; t < NT; ++t) {
        int cur = t & 1;
        if (t + 1 < NT) stageB(cur ^ 1, (t + 1) * 64);
        int kg = lane >> 4;
#pragma unroll
        for (int ks = 0; ks < 2; ++ks) {
            s8v a[4], b[2];
#pragma unroll
            for (int m = 0; m < 4; ++m) {
                int row = m * 16 + (lane & 15);
                unsigned by = *(const unsigned char*)(Sb + row * SBS + t * 8 + ks * 4 + kg);
                a[m] = *(const s8v*)(LUT + by * 16);
            }
#pragma unroll
            for (int n = 0; n < 2; ++n) {
                int row = wc * 32 + n * 16 + (lane & 15);
                b[n] = *(const s8v*)(Bsm[cur] + ((row * 128 + ks * 64 + kg * 16) ^ ((row & 7) << 4)));
            }
#pragma unroll
            for (int m = 0; m < 4; ++m)
#pragma unroll
                for (int n = 0; n < 2; ++n)
                    acc[m][n] = __builtin_amdgcn_mfma_f32_16x16x32_bf16(a[m], b[n], acc[m][n], 0, 0, 0);
        }
        __syncthreads();
    }
    // epilogue: scale by 1/cnt, add bias
#pragma unroll
    for (int m = 0; m < 4; ++m) {
        int rbase = r0 + m * 16 + (lane >> 4) * 4;
        float rc[4];
#pragma unroll
        for (int r = 0; r < 4; ++r) rc[r] = cntrcp[rbase + r];
#pragma unroll
        for (int n = 0; n < 2; ++n) {
            int col = c0 + wc * 32 + n * 16 + (lane & 15);
            float bv = bias[col];
#pragma unroll
            for (int r = 0; r < 4; ++r)
                out[(size_t)(rbase + r) * HH + col] = acc[m][n][r] * rc[r] + bv;
        }
    }
}

extern "C" void kernel_launch(void* const* d_in, const int* in_sizes, int n_in,
                              void* d_out, int out_size, void* d_ws, size_t ws_size,
                              hipStream_t stream) {
    const int*   sm   = (const int*)d_in[0];
    const float* E    = (const float*)d_in[1];
    const int*   pa   = (const int*)d_in[2];
    const float* W    = (const float*)d_in[3];
    const float* bias = (const float*)d_in[4];
    float* out = (float*)d_out;

    char* ws = (char*)d_ws;
    float*         cntrcp = (float*)(ws + 0);           // 65536 B
    u16*           EWt    = (u16*)(ws + 65536);         // 458752 B
    unsigned char* sbytes = (unsigned char*)(ws + 524288);  // 1835008 B

    hipLaunchKernelGGL(k_front, dim3(G1B + NROWS / 64), dim3(256), 0, stream,
                       sm, E, pa, W, EWt, sbytes, cntrcp);
    hipLaunchKernelGGL(k_gemm2, dim3(NROWS / 64, 2), dim3(256), 0, stream,
                       sbytes, EWt, cntrcp, bias, out);
}